// Round 2
// baseline (844.832 us; speedup 1.0000x reference)
//
#include <hip/hip_runtime.h>

// Problem constants (from reference): N=4194304 rows, C=16 classes, EPS=1.0
// Segments: 4 signal (rows >= signal_start), 8 background (rows < signal_start).
// Workspace layout: [0,8) double loss_sum; [8,8+24*4) uint counters:
//   ctr[0..3]  = fn (signal mismatch count per sig segment)
//   ctr[4..7]  = cnt (signal rows per sig segment)
//   ctr[8..15] = fns (background hit count per bg segment)
//   ctr[16..23]= cnt_b (background rows per bg segment)

__global__ void init_ws(double* loss_sum, unsigned int* ctr) {
    if (threadIdx.x == 0) *loss_sum = 0.0;
    if (threadIdx.x < 24) ctr[threadIdx.x] = 0u;
}

// One row per thread. 16384 blocks x 256 threads covers N=4M rows exactly.
// Rationale vs R1 (grid-stride, 1024 blocks): VGPR_Count=28 showed the
// compiler serialized the 8 dwordx4 loads (not enough regs to keep them in
// flight), and occupancy capped at 16 waves/CU. One-row-per-thread gives all
// 8 loads in flight per lane + 32 waves/CU TLP.
__global__ __launch_bounds__(256) void zscore_main(
    const float4* __restrict__ pred,   // N rows x 4 float4 (16 classes)
    const float4* __restrict__ truth,
    const int*    __restrict__ sig_ids,
    const int*    __restrict__ bg_ids,
    int N, int signal_start,
    double* __restrict__ loss_sum,
    unsigned int* __restrict__ ctr)
{
    __shared__ unsigned int s_flag[12];   // p: [0,4)=sig seg, [4,12)=4+bg seg
    __shared__ unsigned int s_cnt[12];
    __shared__ float s_wave_loss[4];

    const int tid = threadIdx.x;
    if (tid < 12) { s_flag[tid] = 0u; s_cnt[tid] = 0u; }
    __syncthreads();

    const int row = blockIdx.x * 256 + tid;
    float local_loss = 0.0f;

    if (row < N) {   // N % 256 == 0 -> wave-uniform, effectively always true
        const float4* pr = pred  + (size_t)row * 4;
        const float4* tr = truth + (size_t)row * 4;
        // Issue all 8 loads up front (no loop-carried reuse -> all in flight).
        float4 p0 = pr[0], p1 = pr[1], p2 = pr[2], p3 = pr[3];
        float4 t0 = tr[0], t1 = tr[1], t2 = tr[2], t3 = tr[3];
        // seg-id load overlaps with the float4 loads
        bool isSig = row >= signal_start;
        int segRaw = isSig ? sig_ids[row - signal_start] : bg_ids[row];

        float v[16] = {p0.x,p0.y,p0.z,p0.w, p1.x,p1.y,p1.z,p1.w,
                       p2.x,p2.y,p2.z,p2.w, p3.x,p3.y,p3.z,p3.w};
        float t[16] = {t0.x,t0.y,t0.z,t0.w, t1.x,t1.y,t1.z,t1.w,
                       t2.x,t2.y,t2.z,t2.w, t3.x,t3.y,t3.z,t3.w};

        // pred argmax (first max wins, matching jnp.argmax) + max for lse
        float pm = v[0]; int am = 0;
        #pragma unroll
        for (int i = 1; i < 16; ++i) { if (v[i] > pm) { pm = v[i]; am = i; } }

        // truth is one-hot: index via sum of i*(t[i]>0.5); pred[tm] via dot
        int tm = 0; float pv = 0.0f;
        #pragma unroll
        for (int i = 0; i < 16; ++i) {
            tm += (t[i] > 0.5f) ? i : 0;
            pv += v[i] * t[i];           // exact: t[i] is 0.0 or 1.0
        }

        // logsumexp
        float s = 0.0f;
        #pragma unroll
        for (int i = 0; i < 16; ++i) s += __expf(v[i] - pm);
        float lse = pm + __logf(s);

        local_loss = lse - pv;  // -(log_softmax[tm])

        // segment statistics: p is wave-uniform (seg boundaries are 64-aligned)
        int p; bool flag;
        if (isSig) { p = segRaw;     flag = (am != tm); }
        else       { p = 4 + segRaw; flag = (am == 0);  }

        int p0l = __builtin_amdgcn_readfirstlane(p);
        bool uni = __all(p == p0l);
        if (uni) {
            unsigned long long fb = __ballot(flag);
            if ((tid & 63) == 0) {
                atomicAdd(&s_cnt[p0l], 64u);
                atomicAdd(&s_flag[p0l], (unsigned int)__popcll(fb));
            }
        } else {
            atomicAdd(&s_cnt[p], 1u);
            if (flag) atomicAdd(&s_flag[p], 1u);
        }
    }

    // reduce local_loss: wave shuffle -> LDS -> block -> global double atomic
    #pragma unroll
    for (int off = 32; off > 0; off >>= 1)
        local_loss += __shfl_down(local_loss, off);
    if ((tid & 63) == 0) s_wave_loss[tid >> 6] = local_loss;
    __syncthreads();

    if (tid == 0) {
        float bl = s_wave_loss[0] + s_wave_loss[1] + s_wave_loss[2] + s_wave_loss[3];
        atomicAdd(loss_sum, (double)bl);
    }
    if (tid < 12) {
        int fIdx = (tid < 4) ? tid       : 8  + (tid - 4);
        int cIdx = (tid < 4) ? 4 + tid   : 16 + (tid - 4);
        if (s_flag[tid]) atomicAdd(&ctr[fIdx], s_flag[tid]);
        if (s_cnt[tid])  atomicAdd(&ctr[cIdx], s_cnt[tid]);
    }
}

__global__ void finalize(const float* __restrict__ w_sig,
                         const float* __restrict__ w_bg,
                         const double* __restrict__ loss_sum,
                         const unsigned int* __restrict__ ctr,
                         float* __restrict__ out, int N)
{
    if (threadIdx.x != 0 || blockIdx.x != 0) return;
    double sig = 0.0, wsum = 0.0;
    for (int s = 0; s < 4; ++s) {
        double cnt = (double)ctr[4 + s];
        double fn  = (double)ctr[s];
        sig  += (cnt - fn) / cnt * (double)w_sig[s];
        wsum += (double)w_sig[s];
    }
    double bg = 0.0;
    for (int s = 0; s < 8; ++s) {
        double fns = (double)ctr[8 + s];
        double cb  = (double)ctr[16 + s];
        bg += sqrt(fns / cb * (double)w_bg[s] + 1.0);  // EPS = 1.0
    }
    double coeff = (wsum - sig) / bg;   // max_score = wsum / sqrt(1.0)
    double loss  = (*loss_sum) / (double)N;
    out[0] = (float)(loss * coeff);
}

extern "C" void kernel_launch(void* const* d_in, const int* in_sizes, int n_in,
                              void* d_out, int out_size, void* d_ws, size_t ws_size,
                              hipStream_t stream) {
    const float* pred   = (const float*)d_in[0];
    const float* truth  = (const float*)d_in[1];
    const float* w_sig  = (const float*)d_in[2];
    const float* w_bg   = (const float*)d_in[3];
    const int*   sigid  = (const int*)d_in[4];
    const int*   bgid   = (const int*)d_in[5];

    const int N = in_sizes[0] / 16;          // rows
    const int signal_start = in_sizes[5];    // == len(background_seg_ids) == B_BG

    double*       loss_sum = (double*)d_ws;
    unsigned int* ctr      = (unsigned int*)((char*)d_ws + 8);

    init_ws<<<1, 64, 0, stream>>>(loss_sum, ctr);

    const int blocks = (N + 255) / 256;      // one row per thread
    zscore_main<<<blocks, 256, 0, stream>>>(
        (const float4*)pred, (const float4*)truth, sigid, bgid,
        N, signal_start, loss_sum, ctr);

    finalize<<<1, 64, 0, stream>>>(w_sig, w_bg, loss_sum, ctr, (float*)d_out, N);
}

// Round 3
// 536.305 us; speedup vs baseline: 1.5753x; 1.5753x over previous
//
#include <hip/hip_runtime.h>

// Workspace layout: [0,8) double loss_sum; [8,8+24*4) uint counters:
//   ctr[0..3]=fn  ctr[4..7]=cnt  ctr[8..15]=fns  ctr[16..23]=cnt_b

__global__ void init_ws(double* loss_sum, unsigned int* ctr) {
    if (threadIdx.x == 0) *loss_sum = 0.0;
    if (threadIdx.x < 24) ctr[threadIdx.x] = 0u;
}

// R3: 2048 blocks x 256 thr, 8 rows/thread, explicit 2-deep pipeline.
// R1 failed: VGPR=28 -> pred-loads/consume/truth-loads chained, 2 HBM RTs
//   per row, only 4 waves/SIMD to hide them -> 170us latency-bound.
// R2 failed: 16K blocks x 25 same-address global atomics serialized -> 474us.
// Here: next row's 8 dwordx4 issue before current row's VALU chain; block
// count stays small so tail atomics stay at R1 cost amortized over 8 rows.
__global__ __launch_bounds__(256, 4) void zscore_main(
    const float4* __restrict__ pred,   // N rows x 4 float4 (16 classes)
    const float4* __restrict__ truth,
    const int*    __restrict__ sig_ids,
    const int*    __restrict__ bg_ids,
    int N, int signal_start,
    double* __restrict__ loss_sum,
    unsigned int* __restrict__ ctr)
{
    __shared__ unsigned int s_flag[12];   // p: [0,4)=sig seg, [4,12)=4+bg seg
    __shared__ unsigned int s_cnt[12];
    __shared__ float s_wave_loss[4];

    const int tid = threadIdx.x;
    if (tid < 12) { s_flag[tid] = 0u; s_cnt[tid] = 0u; }
    __syncthreads();

    const int T = gridDim.x * blockDim.x;
    float local_loss = 0.0f;

    int row = blockIdx.x * blockDim.x + tid;
    bool valid = row < N;   // N,T multiples of 64 -> wave-uniform

    // ---- pipeline registers (current row) ----
    float4 p0, p1, p2, p3, t0, t1, t2, t3;
    int   seg = 0; bool isSig = false;

    if (valid) {
        const float4* pr = pred  + (size_t)row * 4;
        const float4* tr = truth + (size_t)row * 4;
        p0 = pr[0]; p1 = pr[1]; p2 = pr[2]; p3 = pr[3];
        t0 = tr[0]; t1 = tr[1]; t2 = tr[2]; t3 = tr[3];
        isSig = row >= signal_start;
        seg = isSig ? sig_ids[row - signal_start] : bg_ids[row];
    }

    while (valid) {
        // ---- issue NEXT row's loads before consuming current ----
        const int nrow = row + T;
        const bool nvalid = nrow < N;     // wave-uniform
        float4 q0, q1, q2, q3, u0, u1, u2, u3;
        int nseg = 0; bool nIsSig = false;
        if (nvalid) {
            const float4* pr = pred  + (size_t)nrow * 4;
            const float4* tr = truth + (size_t)nrow * 4;
            q0 = pr[0]; q1 = pr[1]; q2 = pr[2]; q3 = pr[3];
            u0 = tr[0]; u1 = tr[1]; u2 = tr[2]; u3 = tr[3];
            nIsSig = nrow >= signal_start;
            nseg = nIsSig ? sig_ids[nrow - signal_start] : bg_ids[nrow];
        }

        // ---- process current row ----
        {
            float v[16] = {p0.x,p0.y,p0.z,p0.w, p1.x,p1.y,p1.z,p1.w,
                           p2.x,p2.y,p2.z,p2.w, p3.x,p3.y,p3.z,p3.w};
            float t[16] = {t0.x,t0.y,t0.z,t0.w, t1.x,t1.y,t1.z,t1.w,
                           t2.x,t2.y,t2.z,t2.w, t3.x,t3.y,t3.z,t3.w};

            // pred argmax (first max wins) + row max
            float pm = v[0]; int am = 0;
            #pragma unroll
            for (int i = 1; i < 16; ++i) { if (v[i] > pm) { pm = v[i]; am = i; } }

            // truth one-hot: class index + pred[tm] as dot product (exact)
            int tm = 0; float pv = 0.0f;
            #pragma unroll
            for (int i = 0; i < 16; ++i) {
                tm += (t[i] > 0.5f) ? i : 0;
                pv += v[i] * t[i];
            }

            float s = 0.0f;
            #pragma unroll
            for (int i = 0; i < 16; ++i) s += __expf(v[i] - pm);
            local_loss += pm + __logf(s) - pv;

            int p; bool flag;
            if (isSig) { p = seg;     flag = (am != tm); }
            else       { p = 4 + seg; flag = (am == 0);  }

            // seg boundaries 64-aligned -> p wave-uniform in practice
            int p0l = __builtin_amdgcn_readfirstlane(p);
            bool uni = __all(p == p0l);
            if (uni) {
                unsigned long long fb = __ballot(flag);
                if ((tid & 63) == 0) {
                    atomicAdd(&s_cnt[p0l], 64u);
                    atomicAdd(&s_flag[p0l], (unsigned int)__popcll(fb));
                }
            } else {
                atomicAdd(&s_cnt[p], 1u);
                if (flag) atomicAdd(&s_flag[p], 1u);
            }
        }

        // ---- rotate pipeline ----
        p0 = q0; p1 = q1; p2 = q2; p3 = q3;
        t0 = u0; t1 = u1; t2 = u2; t3 = u3;
        seg = nseg; isSig = nIsSig;
        row = nrow; valid = nvalid;
    }

    // block reduction of loss
    #pragma unroll
    for (int off = 32; off > 0; off >>= 1)
        local_loss += __shfl_down(local_loss, off);
    if ((tid & 63) == 0) s_wave_loss[tid >> 6] = local_loss;
    __syncthreads();

    if (tid == 0) {
        float bl = s_wave_loss[0] + s_wave_loss[1] + s_wave_loss[2] + s_wave_loss[3];
        atomicAdd(loss_sum, (double)bl);
    }
    if (tid < 12) {
        int fIdx = (tid < 4) ? tid     : 8  + (tid - 4);
        int cIdx = (tid < 4) ? 4 + tid : 16 + (tid - 4);
        if (s_flag[tid]) atomicAdd(&ctr[fIdx], s_flag[tid]);
        if (s_cnt[tid])  atomicAdd(&ctr[cIdx], s_cnt[tid]);
    }
}

__global__ void finalize(const float* __restrict__ w_sig,
                         const float* __restrict__ w_bg,
                         const double* __restrict__ loss_sum,
                         const unsigned int* __restrict__ ctr,
                         float* __restrict__ out, int N)
{
    if (threadIdx.x != 0 || blockIdx.x != 0) return;
    double sig = 0.0, wsum = 0.0;
    for (int s = 0; s < 4; ++s) {
        double cnt = (double)ctr[4 + s];
        double fn  = (double)ctr[s];
        sig  += (cnt - fn) / cnt * (double)w_sig[s];
        wsum += (double)w_sig[s];
    }
    double bg = 0.0;
    for (int s = 0; s < 8; ++s) {
        double fns = (double)ctr[8 + s];
        double cb  = (double)ctr[16 + s];
        bg += sqrt(fns / cb * (double)w_bg[s] + 1.0);  // EPS = 1.0
    }
    double coeff = (wsum - sig) / bg;   // max_score = wsum / sqrt(1.0)
    double loss  = (*loss_sum) / (double)N;
    out[0] = (float)(loss * coeff);
}

extern "C" void kernel_launch(void* const* d_in, const int* in_sizes, int n_in,
                              void* d_out, int out_size, void* d_ws, size_t ws_size,
                              hipStream_t stream) {
    const float* pred   = (const float*)d_in[0];
    const float* truth  = (const float*)d_in[1];
    const float* w_sig  = (const float*)d_in[2];
    const float* w_bg   = (const float*)d_in[3];
    const int*   sigid  = (const int*)d_in[4];
    const int*   bgid   = (const int*)d_in[5];

    const int N = in_sizes[0] / 16;          // rows
    const int signal_start = in_sizes[5];    // == B_BG

    double*       loss_sum = (double*)d_ws;
    unsigned int* ctr      = (unsigned int*)((char*)d_ws + 8);

    init_ws<<<1, 64, 0, stream>>>(loss_sum, ctr);

    const int blocks = 2048;                 // 8 rows/thread at N=4M
    zscore_main<<<blocks, 256, 0, stream>>>(
        (const float4*)pred, (const float4*)truth, sigid, bgid,
        N, signal_start, loss_sum, ctr);

    finalize<<<1, 64, 0, stream>>>(w_sig, w_bg, loss_sum, ctr, (float*)d_out, N);
}